// Round 7
// baseline (256.241 us; speedup 1.0000x reference)
//
#include <hip/hip_runtime.h>

#define BDIM 8
#define NPTS 4096
#define KNEI 20
#define BN (BDIM*NPTS)        // 32768
#define NKCNT (NPTS*KNEI)     // 81920
#define EPSI 1e-5f
#define SLOPE 0.01f

typedef __attribute__((ext_vector_type(8))) short bf16x8;
typedef __attribute__((ext_vector_type(4))) float f32x4;
typedef __attribute__((ext_vector_type(4))) unsigned int u32x4;

// HW packed fp32->bf16 (RNE): D[15:0]=bf16(lo), D[31:16]=bf16(hi). gfx950.
__device__ __forceinline__ unsigned cvtpk(float lo, float hi) {
    unsigned r;
    asm("v_cvt_pk_bf16_f32 %0, %1, %2" : "=v"(r) : "v"(lo), "v"(hi));
    return r;
}
__device__ __forceinline__ float bf2f(unsigned short h) {
    unsigned u = ((unsigned)h) << 16;
    return __builtin_bit_cast(float, u);
}

// async global->LDS DMA, 16 B/lane; per-lane global address (row gather).
__device__ __forceinline__ void async16(const void* g, void* l) {
    __builtin_amdgcn_global_load_lds(
        (const __attribute__((address_space(1))) unsigned int*)g,
        (__attribute__((address_space(3))) unsigned int*)l, 16, 0, 0);
}

// ---------------- K0: u = x*W1a^T, v = x*(W1b-W1a)^T; also W2,W3 -> bf16 ----------------
__global__ __launch_bounds__(256) void k0_uv(const float* __restrict__ x,
        const float* __restrict__ W1, const float* __restrict__ W2,
        const float* __restrict__ W3, unsigned short* __restrict__ u,
        unsigned short* __restrict__ v, unsigned short* __restrict__ w2b,
        unsigned short* __restrict__ w3b) {
    __shared__ float wlds[64 * 129];
    __shared__ float xs[16 * 64];
    int tid = threadIdx.x;
    int m0 = blockIdx.x * 16;
    if (blockIdx.x < 2) {      // one-time weight conversion (before k2 runs)
        const float* Wsrc = (blockIdx.x == 0) ? W2 : W3;
        unsigned short* Wdst = (blockIdx.x == 0) ? w2b : w3b;
        for (int i = tid; i < 2048; i += 256)
            *(unsigned*)(Wdst + 2 * i) = cvtpk(Wsrc[2 * i], Wsrc[2 * i + 1]);
    }
    for (int i = tid; i < 8192; i += 256)
        wlds[(i >> 7) * 129 + (i & 127)] = W1[i];
    for (int i = tid; i < 1024; i += 256)
        xs[i] = x[m0 * 64 + i];
    __syncthreads();
    int o = tid & 63;
    int r0 = tid >> 6;
    float au[4] = {0.f, 0.f, 0.f, 0.f};
    float av[4] = {0.f, 0.f, 0.f, 0.f};
    for (int c = 0; c < 64; ++c) {
        float wa = wlds[o * 129 + c];
        float wb = wlds[o * 129 + 64 + c];
        float wd = wb - wa;
#pragma unroll
        for (int jj = 0; jj < 4; ++jj) {
            float xv = xs[(r0 + jj * 4) * 64 + c];
            au[jj] += xv * wa;
            av[jj] += xv * wd;
        }
    }
#pragma unroll
    for (int jj = 0; jj < 4; ++jj) {
        int m = m0 + r0 + jj * 4;
        u[m * 64 + o] = (unsigned short)cvtpk(au[jj], au[jj]);
        v[m * 64 + o] = (unsigned short)cvtpk(av[jj], av[jj]);
    }
}

// ---- W fragments from preconverted bf16 (plain b128 loads, zero VALU) ----
__device__ __forceinline__ void load_wfrags(const unsigned short* __restrict__ Wb,
        int l15, int q, bf16x8 bw[4][2]) {
#pragma unroll
    for (int mt = 0; mt < 4; ++mt)
#pragma unroll
        for (int kc = 0; kc < 2; ++kc)
            bw[mt][kc] = *(const bf16x8*)(Wb + (mt * 16 + l15) * 64 + kc * 32 + q * 8);
}

// ---- 4-point tile gather: 80 u-rows (swizzled) + v rows (identity) ----
__device__ __forceinline__ void dma_gather4(const unsigned short* __restrict__ u,
        const unsigned short* __restrict__ v, const int* __restrict__ ind,
        unsigned char* tile, unsigned char* vt, int base, int base20, int lane) {
    // v: 8 rows staged, first 4 used (over-read stays inside d_ws)
    async16(v + (size_t)(base + (lane >> 3)) * 64 + (lane & 7) * 8, vt);
    int swz = (lane & 7) ^ ((lane >> 3) & 7);
    int idxr[10];
#pragma unroll
    for (int j = 0; j < 10; ++j)
        idxr[j] = ind[base20 + j * 8 + (lane >> 3)];
#pragma unroll
    for (int j = 0; j < 10; ++j)
        async16(u + (size_t)idxr[j] * 64 + swz * 8, tile + j * 1024);
}

// ---------------- K1: stats1 of h1 = u[ind]+v (single-wave block) ----------------
__global__ __launch_bounds__(64) void k1_stats1(const unsigned short* __restrict__ u,
        const unsigned short* __restrict__ v, const int* __restrict__ ind,
        float* __restrict__ s1p) {
    __shared__ __align__(16) unsigned char tile[10240];
    __shared__ __align__(16) unsigned char vt[1024];
    int lane = threadIdx.x;
    int blk = blockIdx.x;
    int b = blk >> 10;                   // 1024 blocks per batch
    int n0 = (blk & 1023) << 2;          // 4 points
    int base = b * NPTS + n0;
    int base20 = base * 20;
    dma_gather4(u, v, ind, tile, vt, base, base20, lane);
    __syncthreads();
    int c2 = (lane & 31) * 2;
    int rr = lane >> 5;
    float sA = 0.f, qA = 0.f, sB = 0.f, qB = 0.f;
    for (int j = 0; j < 40; ++j) {
        int r = rr + 2 * j;
        int p = (r * 3277) >> 16;        // r/20
        unsigned uu = *(const unsigned*)(tile + r * 128 +
                        (((c2 >> 3) ^ (r & 7)) << 4) + ((c2 & 7) * 2));
        unsigned vv = *(const unsigned*)(vt + p * 128 + c2 * 2);
        float h0 = bf2f((unsigned short)(uu & 0xFFFF)) + bf2f((unsigned short)(vv & 0xFFFF));
        float h1 = bf2f((unsigned short)(uu >> 16)) + bf2f((unsigned short)(vv >> 16));
        sA += h0; qA = fmaf(h0, h0, qA);
        sB += h1; qB = fmaf(h1, h1, qB);
    }
    sA += __shfl_xor(sA, 32, 64); qA += __shfl_xor(qA, 32, 64);
    sB += __shfl_xor(sB, 32, 64); qB += __shfl_xor(qB, 32, 64);
    float* dst = s1p + (blk & 7) * 1024;
    if (lane < 32) {
        atomicAdd(&dst[b * 64 + c2], sA);
        atomicAdd(&dst[b * 64 + c2 + 1], sB);
    } else {
        atomicAdd(&dst[512 + b * 64 + c2], qA);
        atomicAdd(&dst[512 + b * 64 + c2 + 1], qB);
    }
}

// ---------------- kred: s[i] = sum over 8 partials ----------------
__global__ __launch_bounds__(256) void kred(const float* __restrict__ p,
        float* __restrict__ s) {
    int i = blockIdx.x * 256 + threadIdx.x;   // < 1024
    float a = 0.f;
#pragma unroll
    for (int g = 0; g < 8; ++g) a += p[g * 1024 + i];
    s[i] = a;
}

// ------ K2: gather -> norm1+lrelu -> GEMM2 -> shfl stats2 (single-wave) ------
__global__ __launch_bounds__(64) void k2_stats2(const unsigned short* __restrict__ u,
        const unsigned short* __restrict__ v, const int* __restrict__ ind,
        const unsigned short* __restrict__ w2b, const float* __restrict__ s1,
        float* __restrict__ s2p) {
    __shared__ __align__(16) unsigned char tile[10240];
    __shared__ __align__(16) unsigned char vt[1024];
    int lane = threadIdx.x;
    int l15 = lane & 15, q = lane >> 4;
    int blk = blockIdx.x;
    int b = blk >> 10;
    int n0 = (blk & 1023) << 2;
    int base = b * NPTS + n0;
    int base20 = base * 20;
    bf16x8 aw[4][2];
    load_wfrags(w2b, l15, q, aw);
    const float inv = 1.0f / (float)NKCNT;
    float r1[2][8], mr1[2][8];
#pragma unroll
    for (int kc = 0; kc < 2; ++kc)
#pragma unroll
        for (int j = 0; j < 8; ++j) {
            int c = kc * 32 + q * 8 + j;
            float mm = s1[b * 64 + c] * inv;
            float vv = s1[512 + b * 64 + c] * inv - mm * mm;
            float rs = rsqrtf(vv + EPSI);
            r1[kc][j] = rs; mr1[kc][j] = -mm * rs;
        }
    dma_gather4(u, v, ind, tile, vt, base, base20, lane);
    __syncthreads();
    bf16x8 bf[5][2];
#pragma unroll
    for (int nt = 0; nt < 5; ++nt) {
        int row = nt * 16 + l15;
        int p = (row * 3277) >> 16;
#pragma unroll
        for (int kc = 0; kc < 2; ++kc) {
            int phys = (((kc * 4 + q) ^ (row & 7)) << 4);
            bf16x8 ub = *(const bf16x8*)(tile + row * 128 + phys);
            bf16x8 vb = *(const bf16x8*)(vt + p * 128 + kc * 64 + q * 16);
            u32x4 o;
#pragma unroll
            for (int d = 0; d < 4; ++d) {
                float h0 = bf2f((unsigned short)ub[2 * d]) + bf2f((unsigned short)vb[2 * d]);
                float h1 = bf2f((unsigned short)ub[2 * d + 1]) + bf2f((unsigned short)vb[2 * d + 1]);
                float t0 = fmaf(h0, r1[kc][2 * d], mr1[kc][2 * d]);
                float t1 = fmaf(h1, r1[kc][2 * d + 1], mr1[kc][2 * d + 1]);
                t0 = fmaxf(t0, SLOPE * t0);
                t1 = fmaxf(t1, SLOPE * t1);
                o[d] = cvtpk(t0, t1);
            }
            bf[nt][kc] = __builtin_bit_cast(bf16x8, o);
        }
    }
    float* dst = s2p + (blk & 7) * 1024;
#pragma unroll
    for (int mt = 0; mt < 4; ++mt) {
        float s4[4] = {0.f, 0.f, 0.f, 0.f}, q4[4] = {0.f, 0.f, 0.f, 0.f};
#pragma unroll
        for (int nt = 0; nt < 5; ++nt) {
            f32x4 acc = (f32x4){0.f, 0.f, 0.f, 0.f};
            acc = __builtin_amdgcn_mfma_f32_16x16x32_bf16(aw[mt][0], bf[nt][0], acc, 0, 0, 0);
            acc = __builtin_amdgcn_mfma_f32_16x16x32_bf16(aw[mt][1], bf[nt][1], acc, 0, 0, 0);
#pragma unroll
            for (int i = 0; i < 4; ++i) {
                s4[i] += acc[i];
                q4[i] = fmaf(acc[i], acc[i], q4[i]);
            }
        }
#pragma unroll
        for (int m = 1; m <= 8; m <<= 1)
#pragma unroll
            for (int i = 0; i < 4; ++i) {
                s4[i] += __shfl_xor(s4[i], m, 64);
                q4[i] += __shfl_xor(q4[i], m, 64);
            }
        if (l15 == 0) {
#pragma unroll
            for (int i = 0; i < 4; ++i) {
                int c = mt * 16 + q * 4 + i;
                atomicAdd(&dst[b * 64 + c], s4[i]);
                atomicAdd(&dst[512 + b * 64 + c], q4[i]);
            }
        }
    }
}

// -- K3: gather -> a1 -> GEMM2 -> norm2(write-side) -> a2 -> GEMM3 -> max/stats3 -> out --
__global__ __launch_bounds__(64) void k3_gemm3(const unsigned short* __restrict__ u,
        const unsigned short* __restrict__ v, const int* __restrict__ ind,
        const unsigned short* __restrict__ w2b, const unsigned short* __restrict__ w3b,
        const float* __restrict__ s1, const float* __restrict__ s2,
        float* __restrict__ s3p, float* __restrict__ out) {
    __shared__ __align__(16) unsigned char tile[10240];
    __shared__ __align__(16) unsigned char vt[1024];
    int lane = threadIdx.x;
    int l15 = lane & 15, q = lane >> 4;
    int blk = blockIdx.x;
    int b = blk >> 10;
    int n0 = (blk & 1023) << 2;
    int base = b * NPTS + n0;
    int base20 = base * 20;
    bf16x8 aw[4][2];
    load_wfrags(w2b, l15, q, aw);
    const float inv = 1.0f / (float)NKCNT;
    float r1[2][8], mr1[2][8];
#pragma unroll
    for (int kc = 0; kc < 2; ++kc)
#pragma unroll
        for (int j = 0; j < 8; ++j) {
            int c = kc * 32 + q * 8 + j;
            float mm = s1[b * 64 + c] * inv;
            float vv = s1[512 + b * 64 + c] * inv - mm * mm;
            float rs = rsqrtf(vv + EPSI);
            r1[kc][j] = rs; mr1[kc][j] = -mm * rs;
        }
    float r2c[16], mr2c[16];
#pragma unroll
    for (int e = 0; e < 16; ++e) {
        int c = (e >> 2) * 16 + q * 4 + (e & 3);
        float mm = s2[b * 64 + c] * inv;
        float vv = s2[512 + b * 64 + c] * inv - mm * mm;
        float rs = rsqrtf(vv + EPSI);
        r2c[e] = rs; mr2c[e] = -mm * rs;
    }
    dma_gather4(u, v, ind, tile, vt, base, base20, lane);
    __syncthreads();
    // a1 fragments
    bf16x8 bf[5][2];
#pragma unroll
    for (int nt = 0; nt < 5; ++nt) {
        int row = nt * 16 + l15;
        int p = (row * 3277) >> 16;
#pragma unroll
        for (int kc = 0; kc < 2; ++kc) {
            int phys = (((kc * 4 + q) ^ (row & 7)) << 4);
            bf16x8 ub = *(const bf16x8*)(tile + row * 128 + phys);
            bf16x8 vb = *(const bf16x8*)(vt + p * 128 + kc * 64 + q * 16);
            u32x4 o;
#pragma unroll
            for (int d = 0; d < 4; ++d) {
                float h0 = bf2f((unsigned short)ub[2 * d]) + bf2f((unsigned short)vb[2 * d]);
                float h1 = bf2f((unsigned short)ub[2 * d + 1]) + bf2f((unsigned short)vb[2 * d + 1]);
                float t0 = fmaf(h0, r1[kc][2 * d], mr1[kc][2 * d]);
                float t1 = fmaf(h1, r1[kc][2 * d + 1], mr1[kc][2 * d + 1]);
                t0 = fmaxf(t0, SLOPE * t0);
                t1 = fmaxf(t1, SLOPE * t1);
                o[d] = cvtpk(t0, t1);
            }
            bf[nt][kc] = __builtin_bit_cast(bf16x8, o);
        }
    }
    // GEMM2 + write-side norm2+lrelu -> a2 into tile
#pragma unroll
    for (int nt = 0; nt < 5; ++nt) {
        int row = nt * 16 + l15;
        int r7 = row & 7;
#pragma unroll
        for (int mt = 0; mt < 4; ++mt) {
            f32x4 acc = (f32x4){0.f, 0.f, 0.f, 0.f};
            acc = __builtin_amdgcn_mfma_f32_16x16x32_bf16(aw[mt][0], bf[nt][0], acc, 0, 0, 0);
            acc = __builtin_amdgcn_mfma_f32_16x16x32_bf16(aw[mt][1], bf[nt][1], acc, 0, 0, 0);
            float t0 = fmaf(acc[0], r2c[mt * 4 + 0], mr2c[mt * 4 + 0]); t0 = fmaxf(t0, SLOPE * t0);
            float t1 = fmaf(acc[1], r2c[mt * 4 + 1], mr2c[mt * 4 + 1]); t1 = fmaxf(t1, SLOPE * t1);
            float t2 = fmaf(acc[2], r2c[mt * 4 + 2], mr2c[mt * 4 + 2]); t2 = fmaxf(t2, SLOPE * t2);
            float t3 = fmaf(acc[3], r2c[mt * 4 + 3], mr2c[mt * 4 + 3]); t3 = fmaxf(t3, SLOPE * t3);
            unsigned long long pk = (unsigned long long)cvtpk(t0, t1)
                                  | ((unsigned long long)cvtpk(t2, t3) << 32);
            int chunk = mt * 2 + (q >> 1);
            int addr = row * 128 + ((chunk ^ r7) << 4) + (q & 1) * 8;
            *(unsigned long long*)(tile + addr) = pk;
        }
    }
    load_wfrags(w3b, l15, q, aw);
    __syncthreads();
    // GEMM3: read a2 frags, write pre-norm h3 back
#pragma unroll
    for (int nt = 0; nt < 5; ++nt) {
        int row = nt * 16 + l15;
        int r7 = row & 7;
        bf16x8 b0 = *(const bf16x8*)(tile + row * 128 + ((q ^ r7) << 4));
        bf16x8 b1 = *(const bf16x8*)(tile + row * 128 + (((4 + q) ^ r7) << 4));
#pragma unroll
        for (int mt = 0; mt < 4; ++mt) {
            f32x4 acc = (f32x4){0.f, 0.f, 0.f, 0.f};
            acc = __builtin_amdgcn_mfma_f32_16x16x32_bf16(aw[mt][0], b0, acc, 0, 0, 0);
            acc = __builtin_amdgcn_mfma_f32_16x16x32_bf16(aw[mt][1], b1, acc, 0, 0, 0);
            unsigned long long pk = (unsigned long long)cvtpk(acc[0], acc[1])
                                  | ((unsigned long long)cvtpk(acc[2], acc[3]) << 32);
            int chunk = mt * 2 + (q >> 1);
            int addr = row * 128 + ((chunk ^ r7) << 4) + (q & 1) * 8;
            *(unsigned long long*)(tile + addr) = pk;
        }
    }
    __syncthreads();
    // max over k=20 + stats3 from completed h3 tile
    {
        int c2 = (lane & 31) * 2;
        int p0 = lane >> 5;              // 0..1
        int chunkc = c2 >> 3, inb = (c2 & 7) * 2;
        float ss0 = 0.f, ss1 = 0.f, qs0 = 0.f, qs1 = 0.f;
#pragma unroll
        for (int half = 0; half < 2; ++half) {
            int p = p0 + half * 2;
            float mx0 = -3.4e38f, mx1 = -3.4e38f;
            for (int kk = 0; kk < 20; ++kk) {
                int row = p * 20 + kk;
                unsigned dv = *(const unsigned*)(tile + row * 128 +
                               ((chunkc ^ (row & 7)) << 4) + inb);
                float f0 = bf2f((unsigned short)(dv & 0xFFFF));
                float f1 = bf2f((unsigned short)(dv >> 16));
                mx0 = fmaxf(mx0, f0); mx1 = fmaxf(mx1, f1);
                ss0 += f0; qs0 = fmaf(f0, f0, qs0);
                ss1 += f1; qs1 = fmaf(f1, f1, qs1);
            }
            *(float2*)(out + (size_t)(base + p) * 64 + c2) = make_float2(mx0, mx1);
        }
        ss0 += __shfl_xor(ss0, 32, 64); qs0 += __shfl_xor(qs0, 32, 64);
        ss1 += __shfl_xor(ss1, 32, 64); qs1 += __shfl_xor(qs1, 32, 64);
        float* dst = s3p + (blk & 7) * 1024;
        if (lane < 32) {
            atomicAdd(&dst[b * 64 + c2], ss0);
            atomicAdd(&dst[b * 64 + c2 + 1], ss1);
        } else {
            atomicAdd(&dst[512 + b * 64 + c2], qs0);
            atomicAdd(&dst[512 + b * 64 + c2 + 1], qs1);
        }
    }
}

// ---------------- K4: out = lrelu((out - mean3) * rstd3), in place ----------------
__global__ __launch_bounds__(256) void k4_final(float* __restrict__ out,
        const float* __restrict__ s3) {
    int idx = blockIdx.x * 256 + threadIdx.x;
    int c = idx & 63;
    int b = idx >> 18;
    const float inv = 1.0f / (float)NKCNT;
    float mm = s3[b * 64 + c] * inv;
    float vv = s3[512 + b * 64 + c] * inv - mm * mm;
    float r = rsqrtf(vv + EPSI);
    float val = (out[idx] - mm) * r;
    out[idx] = val >= 0.f ? val : SLOPE * val;
}

extern "C" void kernel_launch(void* const* d_in, const int* in_sizes, int n_in,
                              void* d_out, int out_size, void* d_ws, size_t ws_size,
                              hipStream_t stream) {
    const float* x   = (const float*)d_in[0];
    const int*   ind = (const int*)d_in[1];
    const float* W1  = (const float*)d_in[2];
    const float* W2  = (const float*)d_in[3];
    const float* W3  = (const float*)d_in[4];
    float* out = (float*)d_out;

    unsigned short* u = (unsigned short*)d_ws;            // [32768][64] bf16
    unsigned short* v = u + BN * 64;                      // [32768][64] bf16
    float* sp  = (float*)(v + BN * 64);
    float* s1p = sp;               // [8][2][512] partials
    float* s2p = sp + 8192;
    float* s3p = sp + 16384;
    float* s1  = sp + 24576;       // [2][512] reduced
    float* s2  = sp + 25600;
    float* s3  = sp + 26624;
    unsigned short* w2b = (unsigned short*)(sp + 27648);  // [64][64] bf16
    unsigned short* w3b = w2b + 4096;

    hipMemsetAsync(sp, 0, 3 * 8192 * sizeof(float), stream);
    k0_uv<<<dim3(BN / 16), dim3(256), 0, stream>>>(x, W1, W2, W3, u, v, w2b, w3b);
    k1_stats1<<<dim3(BN / 4), dim3(64), 0, stream>>>(u, v, ind, s1p);
    kred<<<dim3(4), dim3(256), 0, stream>>>(s1p, s1);
    k2_stats2<<<dim3(BN / 4), dim3(64), 0, stream>>>(u, v, ind, w2b, s1, s2p);
    kred<<<dim3(4), dim3(256), 0, stream>>>(s2p, s2);
    k3_gemm3<<<dim3(BN / 4), dim3(64), 0, stream>>>(u, v, ind, w2b, w3b, s1, s2, s3p, out);
    kred<<<dim3(4), dim3(256), 0, stream>>>(s3p, s3);
    k4_final<<<dim3(BN * 64 / 256), dim3(256), 0, stream>>>(out, s3);
}